// Round 1
// baseline (103.592 us; speedup 1.0000x reference)
//
#include <hip/hip_runtime.h>

// Sparsemax over last axis. B=16384 rows, N=4096 fp32 logits per row.
//
// Math: out_i = max(z_i - tau, 0) with z = x - max(x), where tau solves
//   f(tau) = sum_i max(z_i - tau, 0) = 1.
// f is convex, decreasing, piecewise linear. Newton from tau0 = -1
// (f(-1) >= 1 since the max element alone contributes 1) converges
// monotonically and terminates EXACTLY once the support set is correct:
//   tau_{n+1} = tau_n + (s - 1)/k,  s = sum_{z>tau}(z - tau), k = |{z>tau}|
// which equals tau = (S_support - 1)/k — the sparsemax closed form.
// Typically ~6-10 iterations for Gaussian rows; capped at 24.

constexpr int kN = 4096;
constexpr int kThreads = 256;          // 4 waves
constexpr int kChunks = kN / (kThreads * 4);  // 4 float4 chunks per thread

__global__ __launch_bounds__(kThreads) void sparsemax_kernel(
    const float* __restrict__ x, float* __restrict__ out) {
  const int row = blockIdx.x;
  const int t = threadIdx.x;
  const size_t base = (size_t)row * kN;
  const float4* xin = reinterpret_cast<const float4*>(x + base);
  float4* xout = reinterpret_cast<float4*>(out + base);

  // Coalesced: instruction j -> lane t reads 16B at (j*256 + t)*16.
  float4 v[kChunks];
#pragma unroll
  for (int j = 0; j < kChunks; ++j) v[j] = xin[j * kThreads + t];

  // ---- row max ----
  float m = -INFINITY;
#pragma unroll
  for (int j = 0; j < kChunks; ++j)
    m = fmaxf(m, fmaxf(fmaxf(v[j].x, v[j].y), fmaxf(v[j].z, v[j].w)));
#pragma unroll
  for (int off = 32; off > 0; off >>= 1) m = fmaxf(m, __shfl_down(m, off));

  __shared__ float smax[4];
  __shared__ float ssum[4];
  __shared__ float scnt[4];
  const int wave = t >> 6;
  const int lane = t & 63;
  if (lane == 0) smax[wave] = m;
  __syncthreads();
  m = fmaxf(fmaxf(smax[0], smax[1]), fmaxf(smax[2], smax[3]));

  // z = x - max (register-resident from here on)
#pragma unroll
  for (int j = 0; j < kChunks; ++j) {
    v[j].x -= m; v[j].y -= m; v[j].z -= m; v[j].w -= m;
  }

  // ---- Newton on tau ----
  float tau = -1.0f;
  for (int it = 0; it < 24; ++it) {
    float s = 0.0f, k = 0.0f;
#pragma unroll
    for (int j = 0; j < kChunks; ++j) {
      float d;
      d = v[j].x - tau; if (d > 0.0f) { s += d; k += 1.0f; }
      d = v[j].y - tau; if (d > 0.0f) { s += d; k += 1.0f; }
      d = v[j].z - tau; if (d > 0.0f) { s += d; k += 1.0f; }
      d = v[j].w - tau; if (d > 0.0f) { s += d; k += 1.0f; }
    }
#pragma unroll
    for (int off = 32; off > 0; off >>= 1) {
      s += __shfl_down(s, off);
      k += __shfl_down(k, off);
    }
    __syncthreads();  // protect ssum/scnt reuse across iterations
    if (lane == 0) { ssum[wave] = s; scnt[wave] = k; }
    __syncthreads();
    s = ssum[0] + ssum[1] + ssum[2] + ssum[3];
    k = scnt[0] + scnt[1] + scnt[2] + scnt[3];
    const float tau_new = tau + (s - 1.0f) / k;  // k >= 1 always (max elt)
    // All threads see identical reduced (s,k) -> uniform branch.
    if (fabsf(tau_new - tau) <= 1e-7f) { tau = tau_new; break; }
    tau = tau_new;
  }

  // ---- output ----
#pragma unroll
  for (int j = 0; j < kChunks; ++j) {
    float4 o;
    o.x = fmaxf(v[j].x - tau, 0.0f);
    o.y = fmaxf(v[j].y - tau, 0.0f);
    o.z = fmaxf(v[j].z - tau, 0.0f);
    o.w = fmaxf(v[j].w - tau, 0.0f);
    xout[j * kThreads + t] = o;
  }
}

extern "C" void kernel_launch(void* const* d_in, const int* in_sizes, int n_in,
                              void* d_out, int out_size, void* d_ws, size_t ws_size,
                              hipStream_t stream) {
  const float* x = (const float*)d_in[0];
  float* out = (float*)d_out;
  const int rows = in_sizes[0] / kN;  // 16384
  sparsemax_kernel<<<rows, kThreads, 0, stream>>>(x, out);
}

// Round 3
// 93.562 us; speedup vs baseline: 1.1072x; 1.1072x over previous
//
#include <hip/hip_runtime.h>

// Sparsemax over last axis. B=16384 rows, N=4096 fp32 logits per row.
//
// out_i = max(x_i - theta, 0), theta = rowmax + tau, tau solves
//   f(tau) = sum_i max(z_i - tau, 0) = 1,  z = x - rowmax.
// f convex decreasing piecewise-linear; Newton from tau0=-1 is monotone
// increasing toward tau* and exact on convergence. Since tau* >= -1, only
// elements with z > -1 ever contribute to any iterate -> compact those few
// (~20 of 4096 for Gaussian rows) into LDS and Newton on wave 0 only, with
// register-resident candidates and shuffle-only reductions (no barriers).
// Fallback to full block-reduce Newton if candidates overflow capacity
// (exactness for arbitrary inputs; never hit for this data).

constexpr int kN = 4096;
constexpr int kThreads = 256;                   // 4 waves
constexpr int kChunks = kN / (kThreads * 4);    // 4 float4 per thread
constexpr int kCap = 256;                       // candidate capacity (4/lane on wave 0)

// native vector type: __builtin_nontemporal_* requires scalar/native-vector,
// not HIP_vector_type<float,4>
typedef float vf4 __attribute__((ext_vector_type(4)));

__global__ __launch_bounds__(kThreads) void sparsemax_kernel(
    const float* __restrict__ x, float* __restrict__ out) {
  const int row = blockIdx.x;
  const int t = threadIdx.x;
  const int wave = t >> 6;
  const int lane = t & 63;
  const size_t base = (size_t)row * kN;
  const vf4* xin = reinterpret_cast<const vf4*>(x + base);
  vf4* xout = reinterpret_cast<vf4*>(out + base);

  __shared__ float smax[4];
  __shared__ float sred[8];      // fallback: per-wave {sum, cnt}
  __shared__ int   scand_n;
  __shared__ float cand[kCap];
  __shared__ float stheta;

  // Coalesced streaming read: instr j -> lane t reads 16B at (j*256+t)*16.
  vf4 v[kChunks];
#pragma unroll
  for (int j = 0; j < kChunks; ++j)
    v[j] = __builtin_nontemporal_load(xin + j * kThreads + t);

  // ---- row max (butterfly -> all lanes, then cross-wave via LDS) ----
  float m = -INFINITY;
#pragma unroll
  for (int j = 0; j < kChunks; ++j)
    m = fmaxf(m, fmaxf(fmaxf(v[j].x, v[j].y), fmaxf(v[j].z, v[j].w)));
#pragma unroll
  for (int off = 32; off > 0; off >>= 1) m = fmaxf(m, __shfl_xor(m, off));

  if (t == 0) scand_n = 0;
  if (lane == 0) smax[wave] = m;
  __syncthreads();
  m = fmaxf(fmaxf(smax[0], smax[1]), fmaxf(smax[2], smax[3]));

  // ---- compact candidates: x > m-1  (i.e. z > -1 >= lower bound of tau*) ----
  const float thresh = m - 1.0f;
#pragma unroll
  for (int j = 0; j < kChunks; ++j) {
    float e;
    e = v[j].x; if (e > thresh) { int i = atomicAdd(&scand_n, 1); if (i < kCap) cand[i] = e - m; }
    e = v[j].y; if (e > thresh) { int i = atomicAdd(&scand_n, 1); if (i < kCap) cand[i] = e - m; }
    e = v[j].z; if (e > thresh) { int i = atomicAdd(&scand_n, 1); if (i < kCap) cand[i] = e - m; }
    e = v[j].w; if (e > thresh) { int i = atomicAdd(&scand_n, 1); if (i < kCap) cand[i] = e - m; }
  }
  __syncthreads();
  const int n = scand_n;   // uniform across block

  float theta;
  if (n <= kCap) {
    // ---- fast path: wave 0 Newton on register-resident candidates ----
    if (wave == 0) {
      // sentinel -2: with tau in [-1, 0], (-2 - tau) < 0 -> never contributes
      float c0 = (lane           < n) ? cand[lane          ] : -2.0f;
      float c1 = (lane + 64      < n) ? cand[lane + 64     ] : -2.0f;
      float c2 = (lane + 128     < n) ? cand[lane + 128    ] : -2.0f;
      float c3 = (lane + 192     < n) ? cand[lane + 192    ] : -2.0f;
      float tau = -1.0f;
      for (int it = 0; it < 32; ++it) {
        float s = 0.0f, k = 0.0f, d;
        d = c0 - tau; if (d > 0.0f) { s += d; k += 1.0f; }
        d = c1 - tau; if (d > 0.0f) { s += d; k += 1.0f; }
        d = c2 - tau; if (d > 0.0f) { s += d; k += 1.0f; }
        d = c3 - tau; if (d > 0.0f) { s += d; k += 1.0f; }
#pragma unroll
        for (int off = 32; off > 0; off >>= 1) {
          s += __shfl_xor(s, off);
          k += __shfl_xor(k, off);
        }
        const float tn = tau + (s - 1.0f) / k;  // k>=1: max elt z=0 > tau* > tau
        if (fabsf(tn - tau) <= 1e-7f) { tau = tn; break; }
        tau = tn;
      }
      if (lane == 0) stheta = m + tau;
    }
    __syncthreads();
    theta = stheta;
  } else {
    // ---- fallback: full block-reduce Newton over all register elements ----
    float tau = -1.0f;
    for (int it = 0; it < 32; ++it) {
      float s = 0.0f, k = 0.0f;
#pragma unroll
      for (int j = 0; j < kChunks; ++j) {
        float d;
        d = v[j].x - m - tau; if (d > 0.0f) { s += d; k += 1.0f; }
        d = v[j].y - m - tau; if (d > 0.0f) { s += d; k += 1.0f; }
        d = v[j].z - m - tau; if (d > 0.0f) { s += d; k += 1.0f; }
        d = v[j].w - m - tau; if (d > 0.0f) { s += d; k += 1.0f; }
      }
#pragma unroll
      for (int off = 32; off > 0; off >>= 1) {
        s += __shfl_xor(s, off);
        k += __shfl_xor(k, off);
      }
      __syncthreads();
      if (lane == 0) { sred[wave] = s; sred[4 + wave] = k; }
      __syncthreads();
      s = sred[0] + sred[1] + sred[2] + sred[3];
      k = sred[4] + sred[5] + sred[6] + sred[7];
      const float tn = tau + (s - 1.0f) / k;
      if (fabsf(tn - tau) <= 1e-7f) { tau = tn; break; }
      tau = tn;
    }
    theta = m + tau;
  }

  // ---- output: out = max(x - theta, 0), streaming stores ----
#pragma unroll
  for (int j = 0; j < kChunks; ++j) {
    vf4 o;
    o.x = fmaxf(v[j].x - theta, 0.0f);
    o.y = fmaxf(v[j].y - theta, 0.0f);
    o.z = fmaxf(v[j].z - theta, 0.0f);
    o.w = fmaxf(v[j].w - theta, 0.0f);
    __builtin_nontemporal_store(o, xout + j * kThreads + t);
  }
}

extern "C" void kernel_launch(void* const* d_in, const int* in_sizes, int n_in,
                              void* d_out, int out_size, void* d_ws, size_t ws_size,
                              hipStream_t stream) {
  const float* x = (const float*)d_in[0];
  float* out = (float*)d_out;
  const int rows = in_sizes[0] / kN;  // 16384
  sparsemax_kernel<<<rows, kThreads, 0, stream>>>(x, out);
}

// Round 4
// 72.062 us; speedup vs baseline: 1.4375x; 1.2983x over previous
//
#include <hip/hip_runtime.h>

// Sparsemax over last axis. B=16384 rows, N=4096 fp32 logits per row.
//
// out_i = max(x_i - theta, 0), theta = rowmax + tau, tau solves
//   f(tau) = sum_i max(z_i - tau, 0) = 1,  z = x - rowmax.
// f convex decreasing piecewise-linear; Newton from tau0=-1 is monotone
// increasing toward tau* and exact on convergence. Since tau* >= -1, only
// elements with z > -1 ever contribute to any iterate -> compact those few
// (~20 of 4096 for Gaussian rows) into LDS and Newton on wave 0 only, with
// register-resident candidates and shuffle-only reductions (no barriers).
// Fallback to full block-reduce Newton if candidates overflow capacity
// (exactness for arbitrary inputs; never hit for this data).
//
// R3 change: loads are REGULAR (cached) — NT loads bypass L2's sector
// aggregation and cost read-stream efficiency; NT kept on stores only.

constexpr int kN = 4096;
constexpr int kThreads = 256;                   // 4 waves
constexpr int kChunks = kN / (kThreads * 4);    // 4 float4 per thread
constexpr int kCap = 256;                       // candidate capacity (4/lane on wave 0)

// native vector type: __builtin_nontemporal_* requires scalar/native-vector
typedef float vf4 __attribute__((ext_vector_type(4)));

__global__ __launch_bounds__(kThreads) void sparsemax_kernel(
    const float* __restrict__ x, float* __restrict__ out) {
  const int row = blockIdx.x;
  const int t = threadIdx.x;
  const int wave = t >> 6;
  const int lane = t & 63;
  const size_t base = (size_t)row * kN;
  const vf4* xin = reinterpret_cast<const vf4*>(x + base);
  vf4* xout = reinterpret_cast<vf4*>(out + base);

  __shared__ float smax[4];
  __shared__ float sred[8];      // fallback: per-wave {sum, cnt}
  __shared__ int   scand_n;
  __shared__ float cand[kCap];
  __shared__ float stheta;

  // Coalesced read: instr j -> lane t reads 16B at (j*256+t)*16. Cached.
  vf4 v[kChunks];
#pragma unroll
  for (int j = 0; j < kChunks; ++j) v[j] = xin[j * kThreads + t];

  // ---- row max (butterfly -> all lanes, then cross-wave via LDS) ----
  float m = -INFINITY;
#pragma unroll
  for (int j = 0; j < kChunks; ++j)
    m = fmaxf(m, fmaxf(fmaxf(v[j].x, v[j].y), fmaxf(v[j].z, v[j].w)));
#pragma unroll
  for (int off = 32; off > 0; off >>= 1) m = fmaxf(m, __shfl_xor(m, off));

  if (t == 0) scand_n = 0;
  if (lane == 0) smax[wave] = m;
  __syncthreads();
  m = fmaxf(fmaxf(smax[0], smax[1]), fmaxf(smax[2], smax[3]));

  // ---- compact candidates: x > m-1  (i.e. z > -1 >= lower bound of tau*) ----
  const float thresh = m - 1.0f;
#pragma unroll
  for (int j = 0; j < kChunks; ++j) {
    float e;
    e = v[j].x; if (e > thresh) { int i = atomicAdd(&scand_n, 1); if (i < kCap) cand[i] = e - m; }
    e = v[j].y; if (e > thresh) { int i = atomicAdd(&scand_n, 1); if (i < kCap) cand[i] = e - m; }
    e = v[j].z; if (e > thresh) { int i = atomicAdd(&scand_n, 1); if (i < kCap) cand[i] = e - m; }
    e = v[j].w; if (e > thresh) { int i = atomicAdd(&scand_n, 1); if (i < kCap) cand[i] = e - m; }
  }
  __syncthreads();
  const int n = scand_n;   // uniform across block

  float theta;
  if (n <= kCap) {
    // ---- fast path: wave 0 Newton on register-resident candidates ----
    if (wave == 0) {
      // sentinel -2: with tau in [-1, 0], (-2 - tau) < 0 -> never contributes
      float c0 = (lane           < n) ? cand[lane          ] : -2.0f;
      float c1 = (lane + 64      < n) ? cand[lane + 64     ] : -2.0f;
      float c2 = (lane + 128     < n) ? cand[lane + 128    ] : -2.0f;
      float c3 = (lane + 192     < n) ? cand[lane + 192    ] : -2.0f;
      float tau = -1.0f;
      for (int it = 0; it < 32; ++it) {
        float s = 0.0f, k = 0.0f, d;
        d = c0 - tau; if (d > 0.0f) { s += d; k += 1.0f; }
        d = c1 - tau; if (d > 0.0f) { s += d; k += 1.0f; }
        d = c2 - tau; if (d > 0.0f) { s += d; k += 1.0f; }
        d = c3 - tau; if (d > 0.0f) { s += d; k += 1.0f; }
#pragma unroll
        for (int off = 32; off > 0; off >>= 1) {
          s += __shfl_xor(s, off);
          k += __shfl_xor(k, off);
        }
        const float tn = tau + (s - 1.0f) / k;  // k>=1: max elt z=0 > tau* > tau
        if (fabsf(tn - tau) <= 1e-7f) { tau = tn; break; }
        tau = tn;
      }
      if (lane == 0) stheta = m + tau;
    }
    __syncthreads();
    theta = stheta;
  } else {
    // ---- fallback: full block-reduce Newton over all register elements ----
    float tau = -1.0f;
    for (int it = 0; it < 32; ++it) {
      float s = 0.0f, k = 0.0f;
#pragma unroll
      for (int j = 0; j < kChunks; ++j) {
        float d;
        d = v[j].x - m - tau; if (d > 0.0f) { s += d; k += 1.0f; }
        d = v[j].y - m - tau; if (d > 0.0f) { s += d; k += 1.0f; }
        d = v[j].z - m - tau; if (d > 0.0f) { s += d; k += 1.0f; }
        d = v[j].w - m - tau; if (d > 0.0f) { s += d; k += 1.0f; }
      }
#pragma unroll
      for (int off = 32; off > 0; off >>= 1) {
        s += __shfl_xor(s, off);
        k += __shfl_xor(k, off);
      }
      __syncthreads();
      if (lane == 0) { sred[wave] = s; sred[4 + wave] = k; }
      __syncthreads();
      s = sred[0] + sred[1] + sred[2] + sred[3];
      k = sred[4] + sred[5] + sred[6] + sred[7];
      const float tn = tau + (s - 1.0f) / k;
      if (fabsf(tn - tau) <= 1e-7f) { tau = tn; break; }
      tau = tn;
    }
    theta = m + tau;
  }

  // ---- output: out = max(x - theta, 0), streaming (nt) stores ----
#pragma unroll
  for (int j = 0; j < kChunks; ++j) {
    vf4 o;
    o.x = fmaxf(v[j].x - theta, 0.0f);
    o.y = fmaxf(v[j].y - theta, 0.0f);
    o.z = fmaxf(v[j].z - theta, 0.0f);
    o.w = fmaxf(v[j].w - theta, 0.0f);
    __builtin_nontemporal_store(o, xout + j * kThreads + t);
  }
}

extern "C" void kernel_launch(void* const* d_in, const int* in_sizes, int n_in,
                              void* d_out, int out_size, void* d_ws, size_t ws_size,
                              hipStream_t stream) {
  const float* x = (const float*)d_in[0];
  float* out = (float*)d_out;
  const int rows = in_sizes[0] / kN;  // 16384
  sparsemax_kernel<<<rows, kThreads, 0, stream>>>(x, out);
}